// Round 1
// baseline (10299.735 us; speedup 1.0000x reference)
//
#include <hip/hip_runtime.h>
#include <stdint.h>

#define DD 50
#define GG 200
#define TT 1024
#define NB 8

typedef _Float16 half_t;
typedef __attribute__((ext_vector_type(2))) _Float16 half2_t;

__device__ __forceinline__ float sigmoid_f(float x) {
    float e = __builtin_amdgcn_exp2f(-1.4426950408889634f * x);   // exp(-x)
    return __builtin_amdgcn_rcpf(1.0f + e);
}
__device__ __forceinline__ float tanh_f(float x) {
    float e = __builtin_amdgcn_exp2f(2.8853900817779268f * x);    // exp(2x)
    return 1.0f - 2.0f * __builtin_amdgcn_rcpf(1.0f + e);
}

__device__ __forceinline__ uint32_t packh(float a, float b) {
    half2_t h;
    h[0] = (half_t)a; h[1] = (half_t)b;
    return __builtin_bit_cast(uint32_t, h);
}
__device__ __forceinline__ float dot2f(uint32_t a, uint32_t b, float c) {
#if __has_builtin(__builtin_amdgcn_fdot2)
    return __builtin_amdgcn_fdot2(__builtin_bit_cast(half2_t, a),
                                  __builtin_bit_cast(half2_t, b), c, false);
#else
    half2_t x = __builtin_bit_cast(half2_t, a), y = __builtin_bit_cast(half2_t, b);
    return c + (float)x[0] * (float)y[0] + (float)x[1] * (float)y[1];
#endif
}
__device__ __forceinline__ uint32_t rl_u32(uint32_t v, int lane) {
    return (uint32_t)__builtin_amdgcn_readlane((int)v, lane);
}
__device__ __forceinline__ float rl_f32(float v, int lane) {
    return __int_as_float(__builtin_amdgcn_readlane(__float_as_int(v), lane));
}

__global__ __launch_bounds__(256, 2)
void lstm_seq_kernel(const float* __restrict__ x,
                     const float* __restrict__ W_ih1, const float* __restrict__ W_hh1,
                     const float* __restrict__ b_ih1, const float* __restrict__ b_hh1,
                     const float* __restrict__ W_ih2, const float* __restrict__ W_hh2,
                     const float* __restrict__ b_ih2, const float* __restrict__ b_hh2,
                     const float* __restrict__ W_lin, const float* __restrict__ b_lin,
                     float* __restrict__ out)
{
    const int tid  = threadIdx.x;
    const int lane = tid & 63;
    const int bg0  = blockIdx.x * NB;

    const int g = tid;
    const bool is_gate = (tid < GG);
    const int gtype = g / DD;   // 0:i 1:f 2:g 3:o (uniform per thread)

    // ---- per-thread register weights (f16-pair packed) ----
    float w1x0 = 0.f, w1x1 = 0.f, bias1 = 0.f, bias2 = 0.f;
    uint32_t wh1p[25], wi2p[25], wh2p[25];
    if (is_gate) {
        w1x0  = W_ih1[g * 2 + 0];
        w1x1  = W_ih1[g * 2 + 1];
        bias1 = b_ih1[g] + b_hh1[g];
        bias2 = b_ih2[g] + b_hh2[g];
#pragma unroll
        for (int k = 0; k < 25; ++k) {
            wh1p[k] = packh(W_hh1[g * DD + 2 * k], W_hh1[g * DD + 2 * k + 1]);
            wi2p[k] = packh(W_ih2[g * DD + 2 * k], W_ih2[g * DD + 2 * k + 1]);
            wh2p[k] = packh(W_hh2[g * DD + 2 * k], W_hh2[g * DD + 2 * k + 1]);
        }
    }
    // linear head weights per lane (pairs over j)
    uint32_t wl0p = 0, wl1p = 0;
    if (lane < 25) {
        wl0p = packh(W_lin[2 * lane],      W_lin[2 * lane + 1]);
        wl1p = packh(W_lin[DD + 2 * lane], W_lin[DD + 2 * lane + 1]);
    }
    const float bl0 = b_lin[0], bl1 = b_lin[1];

    // ---- LDS state ----
    __shared__ uint32_t h1p[NB][32];       // h1 as f16 pairs (25 used)
    __shared__ uint32_t h2p[NB][32];       // h2 as f16 pairs
    __shared__ float    c1s[NB][DD + 2];
    __shared__ float    c2s[NB][DD + 2];
    __shared__ float    gsh[NB][GG];       // activated gates (reused L1/L2)

    for (int i = tid; i < NB * 32; i += 256) { ((uint32_t*)h1p)[i] = 0u; ((uint32_t*)h2p)[i] = 0u; }
    for (int i = tid; i < NB * (DD + 2); i += 256) { ((float*)c1s)[i] = 0.f; ((float*)c2s)[i] = 0.f; }
    __syncthreads();

    for (int t = 0; t < TT; ++t) {
        // ---- stage x(t) and h1(t-1), h2(t-1) pairs into lanes ----
        float xst = 0.f;
        if (lane < 16)
            xst = x[(size_t)(bg0 + (lane >> 1)) * (TT * 2) + t * 2 + (lane & 1)];

        uint32_t s1[NB], s2[NB];
#pragma unroll
        for (int b = 0; b < NB; ++b) {
            s1[b] = (lane < 25) ? h1p[b][lane] : 0u;
            s2[b] = (lane < 25) ? h2p[b][lane] : 0u;
        }

        // ---- phase A: layer-1 gates ----
        float acc[NB];
        if (is_gate) {
#pragma unroll
            for (int b = 0; b < NB; ++b)
                acc[b] = bias1 + w1x0 * rl_f32(xst, 2 * b) + w1x1 * rl_f32(xst, 2 * b + 1);
#pragma unroll
            for (int k = 0; k < 25; ++k) {
#pragma unroll
                for (int b = 0; b < NB; ++b)
                    acc[b] = dot2f(rl_u32(s1[b], k), wh1p[k], acc[b]);
            }
#pragma unroll
            for (int b = 0; b < NB; ++b)
                gsh[b][g] = (gtype == 2) ? tanh_f(acc[b]) : sigmoid_f(acc[b]);
        }
        __syncthreads();   // 1

        // ---- phase B: layer-1 state update ----
        for (int idx = tid; idx < NB * DD; idx += 256) {
            int b = idx / DD, j = idx - b * DD;
            float gi = gsh[b][j], gf = gsh[b][DD + j], gG = gsh[b][2 * DD + j], go = gsh[b][3 * DD + j];
            float c  = c1s[b][j];
            float cn = gf * c + gi * gG;
            float hn = go * tanh_f(cn);
            c1s[b][j] = cn;
            ((half_t*)h1p[b])[j] = (half_t)hn;
        }
        __syncthreads();   // 2

        // ---- stage h1(t) ----
        uint32_t s1n[NB];
#pragma unroll
        for (int b = 0; b < NB; ++b)
            s1n[b] = (lane < 25) ? h1p[b][lane] : 0u;

        // ---- phase C: layer-2 gates ----
        if (is_gate) {
#pragma unroll
            for (int b = 0; b < NB; ++b) acc[b] = bias2;
#pragma unroll
            for (int k = 0; k < 25; ++k) {
#pragma unroll
                for (int b = 0; b < NB; ++b) {
                    acc[b] = dot2f(rl_u32(s1n[b], k), wi2p[k], acc[b]);
                    acc[b] = dot2f(rl_u32(s2[b],  k), wh2p[k], acc[b]);
                }
            }
#pragma unroll
            for (int b = 0; b < NB; ++b)
                gsh[b][g] = (gtype == 2) ? tanh_f(acc[b]) : sigmoid_f(acc[b]);
        }
        __syncthreads();   // 3

        // ---- phase D: layer-2 state update ----
        for (int idx = tid; idx < NB * DD; idx += 256) {
            int b = idx / DD, j = idx - b * DD;
            float gi = gsh[b][j], gf = gsh[b][DD + j], gG = gsh[b][2 * DD + j], go = gsh[b][3 * DD + j];
            float c  = c2s[b][j];
            float cn = gf * c + gi * gG;
            float hn = go * tanh_f(cn);
            c2s[b][j] = cn;
            ((half_t*)h2p[b])[j] = (half_t)hn;
        }
        __syncthreads();   // 4

        // ---- phase E: linear head; wave w handles b = 2w, 2w+1 ----
        {
            int w = tid >> 6;
#pragma unroll
            for (int bb = 0; bb < 2; ++bb) {
                int b = 2 * w + bb;
                uint32_t hp = (lane < 25) ? h2p[b][lane] : 0u;
                float p0 = dot2f(hp, wl0p, 0.f);
                float p1 = dot2f(hp, wl1p, 0.f);
#pragma unroll
                for (int m = 1; m <= 16; m <<= 1) {
                    p0 += __shfl_xor(p0, m, 64);
                    p1 += __shfl_xor(p1, m, 64);
                }
                if (lane == 0) {
                    size_t o = ((size_t)(bg0 + b) * TT + t) * 2;
                    out[o]     = p0 + bl0;
                    out[o + 1] = p1 + bl1;
                }
            }
        }
        // no extra barrier needed: next-iter writers are separated by barriers 1-4
    }
}

extern "C" void kernel_launch(void* const* d_in, const int* in_sizes, int n_in,
                              void* d_out, int out_size, void* d_ws, size_t ws_size,
                              hipStream_t stream) {
    const float* x     = (const float*)d_in[0];
    const float* W_ih1 = (const float*)d_in[1];
    const float* W_hh1 = (const float*)d_in[2];
    const float* b_ih1 = (const float*)d_in[3];
    const float* b_hh1 = (const float*)d_in[4];
    const float* W_ih2 = (const float*)d_in[5];
    const float* W_hh2 = (const float*)d_in[6];
    const float* b_ih2 = (const float*)d_in[7];
    const float* b_hh2 = (const float*)d_in[8];
    const float* W_lin = (const float*)d_in[9];
    const float* b_lin = (const float*)d_in[10];
    float* out = (float*)d_out;

    const int B = in_sizes[0] / (TT * 2);   // 4096
    const int blocks = B / NB;              // 512

    hipLaunchKernelGGL(lstm_seq_kernel, dim3(blocks), dim3(256), 0, stream,
                       x, W_ih1, W_hh1, b_ih1, b_hh1,
                       W_ih2, W_hh2, b_ih2, b_hh2, W_lin, b_lin, out);
}

// Round 2
// 2474.727 us; speedup vs baseline: 4.1620x; 4.1620x over previous
//
#include <hip/hip_runtime.h>
#include <stdint.h>

#define DD 50
#define TT 1024
#define NB 16            // batch rows per block (= MFMA M)

typedef _Float16 half_t;
typedef __attribute__((ext_vector_type(8))) _Float16 f16x8;
typedef __attribute__((ext_vector_type(4))) float    f32x4;

// LDS row strides in f16 units; +8 pad → row stride % 32 banks = 4 dwords → 2-way (free)
#define A1S 72           // K=64 (h1 | x | pad)
#define A2S 136          // K=128 (h1_new | pad | h2_prev | pad)
#define GSW 212          // activated-gates buffer width (208 cols used, pad vs bank alias)

__device__ __forceinline__ float rcp_f(float x)  { return __builtin_amdgcn_rcpf(x); }
__device__ __forceinline__ float exp2_f(float x) { return __builtin_amdgcn_exp2f(x); }

// isT ? tanh(v) : sigmoid(v); m = isT ? 2*log2(e) : -log2(e)
__device__ __forceinline__ float act_f(float v, float m, bool isT) {
    float s = rcp_f(1.0f + exp2_f(m * v));
    return isT ? (1.0f - 2.0f * s) : s;
}
__device__ __forceinline__ float tanh_f(float v) {
    return 1.0f - 2.0f * rcp_f(1.0f + exp2_f(2.8853901f * v));
}

__global__ __launch_bounds__(256, 1)
void lstm_mfma_kernel(const float* __restrict__ x,
                      const float* __restrict__ W_ih1, const float* __restrict__ W_hh1,
                      const float* __restrict__ b_ih1, const float* __restrict__ b_hh1,
                      const float* __restrict__ W_ih2, const float* __restrict__ W_hh2,
                      const float* __restrict__ b_ih2, const float* __restrict__ b_hh2,
                      const float* __restrict__ W_lin, const float* __restrict__ b_lin,
                      float* __restrict__ out)
{
    const int tid   = threadIdx.x;
    const int lane  = tid & 63;
    const int w     = tid >> 6;
    const int bg0   = blockIdx.x * NB;
    const int cl    = lane & 15;          // A-row / B-col within tile / C-col
    const int kg    = (lane >> 4) * 8;    // k base within a 32-wide k-tile
    const int rbase = (lane >> 4) * 4;    // C-row base

    __shared__ half_t A1[NB][A1S];        // [h1_prev(50) | x(2) | 0...]
    __shared__ half_t A2[NB][A2S];        // [h1_new(50) | 0 | h2_prev(50)@64 | 0...]
    __shared__ float  gs[NB][GSW];        // activated gates

    // wave -> N-tile assignment over 13 tiles (cols 0..207): (4,3,3,3)
    const int cnt   = (w == 0) ? 4 : 3;
    const int tbase = (w == 0) ? 0 : 3 * w + 1;   // 0,4,7,10

    // ---- per-lane B fragments (weights), biases, activation constants ----
    int   gcol[4];
    f16x8 b1f[4][2];
    f16x8 b2f[4][4];
    float bias1v[4], bias2v[4], mAv[4];
    bool  isTv[4], isHead[4];

#pragma unroll
    for (int i = 0; i < 4; ++i) {
        const int g = (tbase + i) * 16 + cl;     // global gate/head column
        gcol[i] = g;
        const bool valid = (g < 200);
        const int  gt    = valid ? (g / DD) : 0;
        isTv[i]   = valid && (gt == 2);
        mAv[i]    = isTv[i] ? 2.8853901f : -1.4426950f;
        isHead[i] = (g == 200) || (g == 201);
        bias1v[i] = valid ? (b_ih1[g] + b_hh1[g]) : 0.f;
        bias2v[i] = valid ? (b_ih2[g] + b_hh2[g]) : (isHead[i] ? b_lin[g - 200] : 0.f);
#pragma unroll
        for (int kt = 0; kt < 2; ++kt)
#pragma unroll
            for (int j = 0; j < 8; ++j) {
                const int k = kt * 32 + kg + j;
                float v = 0.f;
                if (valid) {
                    if (k < DD)          v = W_hh1[g * DD + k];
                    else if (k < DD + 2) v = W_ih1[g * 2 + (k - DD)];
                }
                b1f[i][kt][j] = (half_t)v;
            }
#pragma unroll
        for (int kt = 0; kt < 4; ++kt)
#pragma unroll
            for (int j = 0; j < 8; ++j) {
                const int k = kt * 32 + kg + j;
                float v = 0.f;
                if (k < DD) {
                    if (valid) v = W_ih2[g * DD + k];
                } else if (k >= 64 && k < 64 + DD) {
                    const int kk = k - 64;
                    if (valid)          v = W_hh2[g * DD + kk];
                    else if (isHead[i]) v = W_lin[(g - 200) * DD + kk];
                }
                b2f[i][kt][j] = (half_t)v;
            }
    }

    // ---- update-phase item mapping (static across t) + c-state in registers ----
    int  ub[4], uj[4];
    bool uv[4];
    float c1r[4] = {0.f, 0.f, 0.f, 0.f};
    float c2r[4] = {0.f, 0.f, 0.f, 0.f};
#pragma unroll
    for (int s = 0; s < 4; ++s) {
        const int item = tid + 256 * s;
        uv[s] = (item < NB * DD);
        int b = item / DD;
        int j = item - b * DD;
        if (!uv[s]) { b = 0; j = 0; }
        ub[s] = b; uj[s] = j;
    }

    // ---- zero state, stage x(0) ----
    for (int idx = tid; idx < NB * A1S; idx += 256) ((half_t*)A1)[idx] = (half_t)0.f;
    for (int idx = tid; idx < NB * A2S; idx += 256) ((half_t*)A2)[idx] = (half_t)0.f;
    __syncthreads();
    if (tid < NB) {
        const float2 xv = ((const float2*)x)[(size_t)(bg0 + tid) * TT];
        A1[tid][DD]     = (half_t)xv.x;
        A1[tid][DD + 1] = (half_t)xv.y;
    }
    __syncthreads();

    // ---- sequential time loop; t == TT is the head-only finale ----
    for (int t = 0; t <= TT; ++t) {
        const bool full = (t < TT);

        // GEMM2 part B first: k-tiles 2,3 read h2_prev (ready since bar4 of t-1)
        f32x4 acc2[4];
#pragma unroll
        for (int i = 0; i < 4; ++i) {
            f32x4 v = {bias2v[i], bias2v[i], bias2v[i], bias2v[i]};
            acc2[i] = v;
        }
#pragma unroll
        for (int kt = 2; kt < 4; ++kt) {
            const f16x8 a = *(const f16x8*)&A2[cl][kt * 32 + kg];
#pragma unroll
            for (int i = 0; i < 4; ++i)
                if (i < cnt)
                    acc2[i] = __builtin_amdgcn_mfma_f32_16x16x32_f16(a, b2f[i][kt], acc2[i], 0, 0, 0);
        }

        // GEMM1: gates1 = [h1_prev | x] @ B1
        if (full) {
            f32x4 acc1[4];
#pragma unroll
            for (int i = 0; i < 4; ++i) {
                f32x4 v = {bias1v[i], bias1v[i], bias1v[i], bias1v[i]};
                acc1[i] = v;
            }
#pragma unroll
            for (int kt = 0; kt < 2; ++kt) {
                const f16x8 a = *(const f16x8*)&A1[cl][kt * 32 + kg];
#pragma unroll
                for (int i = 0; i < 4; ++i)
                    if (i < cnt)
                        acc1[i] = __builtin_amdgcn_mfma_f32_16x16x32_f16(a, b1f[i][kt], acc1[i], 0, 0, 0);
            }
#pragma unroll
            for (int i = 0; i < 4; ++i)
                if (i < cnt) {
#pragma unroll
                    for (int r = 0; r < 4; ++r)
                        gs[rbase + r][gcol[i]] = act_f(acc1[i][r], mAv[i], isTv[i]);
                }
        }
        __syncthreads();   // bar1: gates1 visible

        // update1: c1/h1; also prefetch x(t+1) into A1
        if (full) {
#pragma unroll
            for (int s = 0; s < 4; ++s)
                if (uv[s]) {
                    const int b = ub[s], j = uj[s];
                    const float gi = gs[b][j];
                    const float gf = gs[b][DD + j];
                    const float gg = gs[b][2 * DD + j];
                    const float go = gs[b][3 * DD + j];
                    const float cn = gf * c1r[s] + gi * gg;
                    c1r[s] = cn;
                    const half_t hn = (half_t)(go * tanh_f(cn));
                    A1[b][j] = hn;     // for GEMM1(t+1)
                    A2[b][j] = hn;     // for GEMM2 part A (this step)
                }
            if (tid < NB && (t + 1) < TT) {
                const float2 xv = ((const float2*)x)[(size_t)(bg0 + tid) * TT + (t + 1)];
                A1[tid][DD]     = (half_t)xv.x;
                A1[tid][DD + 1] = (half_t)xv.y;
            }
        }
        __syncthreads();   // bar2: h1_new visible

        // GEMM2 part A: k-tiles 0,1 read h1_new (head cols have zero weights here)
#pragma unroll
        for (int kt = 0; kt < 2; ++kt) {
            const f16x8 a = *(const f16x8*)&A2[cl][kt * 32 + kg];
#pragma unroll
            for (int i = 0; i < 4; ++i)
                if (i < cnt)
                    acc2[i] = __builtin_amdgcn_mfma_f32_16x16x32_f16(a, b2f[i][kt], acc2[i], 0, 0, 0);
        }
        // epilogue: head columns -> out(t-1); gate columns -> activated gs
#pragma unroll
        for (int i = 0; i < 4; ++i)
            if (i < cnt) {
                if (isHead[i] && t >= 1) {
#pragma unroll
                    for (int r = 0; r < 4; ++r)
                        out[((size_t)(bg0 + rbase + r) * TT + (t - 1)) * 2 + (gcol[i] - 200)] = acc2[i][r];
                }
                if (full) {
#pragma unroll
                    for (int r = 0; r < 4; ++r)
                        gs[rbase + r][gcol[i]] = act_f(acc2[i][r], mAv[i], isTv[i]);
                }
            }
        __syncthreads();   // bar3: gates2 visible

        // update2: c2/h2 -> A2 cols 64..113
        if (full) {
#pragma unroll
            for (int s = 0; s < 4; ++s)
                if (uv[s]) {
                    const int b = ub[s], j = uj[s];
                    const float gi = gs[b][j];
                    const float gf = gs[b][DD + j];
                    const float gg = gs[b][2 * DD + j];
                    const float go = gs[b][3 * DD + j];
                    const float cn = gf * c2r[s] + gi * gg;
                    c2r[s] = cn;
                    A2[b][64 + j] = (half_t)(go * tanh_f(cn));
                }
        }
        __syncthreads();   // bar4: h2_new visible for next iteration's part B
    }
}

extern "C" void kernel_launch(void* const* d_in, const int* in_sizes, int n_in,
                              void* d_out, int out_size, void* d_ws, size_t ws_size,
                              hipStream_t stream) {
    const float* x     = (const float*)d_in[0];
    const float* W_ih1 = (const float*)d_in[1];
    const float* W_hh1 = (const float*)d_in[2];
    const float* b_ih1 = (const float*)d_in[3];
    const float* b_hh1 = (const float*)d_in[4];
    const float* W_ih2 = (const float*)d_in[5];
    const float* W_hh2 = (const float*)d_in[6];
    const float* b_ih2 = (const float*)d_in[7];
    const float* b_hh2 = (const float*)d_in[8];
    const float* W_lin = (const float*)d_in[9];
    const float* b_lin = (const float*)d_in[10];
    float* out = (float*)d_out;

    const int B = in_sizes[0] / (TT * 2);   // 4096
    const int blocks = B / NB;              // 256

    hipLaunchKernelGGL(lstm_mfma_kernel, dim3(blocks), dim3(256), 0, stream,
                       x, W_ih1, W_hh1, b_ih1, b_hh1,
                       W_ih2, W_hh2, b_ih2, b_hh2, W_lin, b_lin, out);
}

// Round 3
// 2263.867 us; speedup vs baseline: 4.5496x; 1.0931x over previous
//
#include <hip/hip_runtime.h>
#include <stdint.h>

#define DD 50
#define TT 1024
#define NB 16            // batch rows per block (= MFMA M)
#define KF 32            // x-prefetch / out-flush chunk (steps)

typedef _Float16 half_t;
typedef __attribute__((ext_vector_type(8))) _Float16 f16x8;
typedef __attribute__((ext_vector_type(4))) float    f32x4;

#define A1S 72           // K=64 (h1 | x | 1 | pad)
#define A2S 136          // K=128 (h1_new | 1@52 | h2_prev@64 | pad)
#define GT_S 36          // gsT row stride in f32: 16 rows + pad; 144B = 16B-aligned, 2-way banks (free)

__device__ __forceinline__ float rcp_f(float x)  { return __builtin_amdgcn_rcpf(x); }
__device__ __forceinline__ float exp2_f(float x) { return __builtin_amdgcn_exp2f(x); }
__device__ __forceinline__ float sig_f(float v)  { return rcp_f(1.0f + exp2_f(-1.4426950f * v)); }
__device__ __forceinline__ float tanh_f(float v) { return 1.0f - 2.0f * rcp_f(1.0f + exp2_f(2.8853901f * v)); }

__global__ __launch_bounds__(256, 1)
void lstm_mfma_kernel(const float* __restrict__ x,
                      const float* __restrict__ W_ih1, const float* __restrict__ W_hh1,
                      const float* __restrict__ b_ih1, const float* __restrict__ b_hh1,
                      const float* __restrict__ W_ih2, const float* __restrict__ W_hh2,
                      const float* __restrict__ b_ih2, const float* __restrict__ b_hh2,
                      const float* __restrict__ W_lin, const float* __restrict__ b_lin,
                      float* __restrict__ out)
{
    const int tid   = threadIdx.x;
    const int lane  = tid & 63;
    const int w     = tid >> 6;
    const int bg0   = blockIdx.x * NB;
    const int cl    = lane & 15;          // A-row / B-col within tile / C-col
    const int kg    = (lane >> 4) * 8;    // k base within a 32-wide k-tile
    const int rbase = (lane >> 4) * 4;    // C-row base

    __shared__ half_t A1[NB][A1S];        // [h1_prev(50) | x(2) | 1.0 | 0...]
    __shared__ half_t A2[NB][A2S];        // [h1_new(50) | 0 | 1.0@52 | 0 | h2_prev(50)@64 | 0...]
    __shared__ float  gsT[208][GT_S];     // raw gates, transposed: [col][row]
    __shared__ float  obuf[NB][KF * 2];   // output ring: [row][slot*2+c], 256B rows
    __shared__ float  xbuf[2][NB][KF * 2];// x chunks, double-buffered

    // wave -> N-tile assignment over 13 tiles (cols 0..207): (4,3,3,3)
    const int cnt   = (w == 0) ? 4 : 3;
    const int tbase = (w == 0) ? 0 : 3 * w + 1;   // 0,4,7,10

    // ---- per-lane B fragments (weights + bias row 52), head folded in ----
    int   gcol[4];
    bool  isHead[4];
    f16x8 b1f[4][2];
    f16x8 b2f[4][4];

#pragma unroll
    for (int i = 0; i < 4; ++i) {
        const int g = (tbase + i) * 16 + cl;
        gcol[i] = g;
        const bool valid = (g < 200);
        isHead[i] = (g == 200) || (g == 201);
#pragma unroll
        for (int kt = 0; kt < 2; ++kt)
#pragma unroll
            for (int j = 0; j < 8; ++j) {
                const int k = kt * 32 + kg + j;
                float v = 0.f;
                if (valid) {
                    if (k < DD)          v = W_hh1[g * DD + k];
                    else if (k < DD + 2) v = W_ih1[g * 2 + (k - DD)];
                    else if (k == 52)    v = b_ih1[g] + b_hh1[g];
                }
                b1f[i][kt][j] = (half_t)v;
            }
#pragma unroll
        for (int kt = 0; kt < 4; ++kt)
#pragma unroll
            for (int j = 0; j < 8; ++j) {
                const int k = kt * 32 + kg + j;
                float v = 0.f;
                if (k < DD) {
                    if (valid) v = W_ih2[g * DD + k];
                } else if (k == 52) {
                    if (valid)          v = b_ih2[g] + b_hh2[g];
                    else if (isHead[i]) v = b_lin[g - 200];
                } else if (k >= 64 && k < 64 + DD) {
                    const int kk = k - 64;
                    if (valid)          v = W_hh2[g * DD + kk];
                    else if (isHead[i]) v = W_lin[(g - 200) * DD + kk];
                }
                b2f[i][kt][j] = (half_t)v;
            }
    }

    // ---- update-phase item mapping (static) + c-state in registers ----
    int  ub[4], uj[4];
    bool uv[4];
    float c1r[4] = {0.f, 0.f, 0.f, 0.f};
    float c2r[4] = {0.f, 0.f, 0.f, 0.f};
#pragma unroll
    for (int s = 0; s < 4; ++s) {
        const int item = tid + 256 * s;
        uv[s] = (item < NB * DD);
        int b = item / DD;
        int j = item - b * DD;
        if (!uv[s]) { b = 0; j = 0; }
        ub[s] = b; uj[s] = j;
    }

    const int xb = tid >> 4;      // x/out row this thread services
    const int xq = tid & 15;      // 16B quarter within the 64-float chunk row
    const float* xrow = x + (size_t)(bg0 + xb) * (TT * 2);

    // ---- init: zero state, const-1 columns, chunk 0, x(0) ----
    for (int idx = tid; idx < NB * A1S; idx += 256) ((half_t*)A1)[idx] = (half_t)0.f;
    for (int idx = tid; idx < NB * A2S; idx += 256) ((half_t*)A2)[idx] = (half_t)0.f;
    const f32x4 x0 = *(const f32x4*)(xrow + xq * 4);
    __syncthreads();
    if (tid < NB) { A1[tid][52] = (half_t)1.0f; A2[tid][52] = (half_t)1.0f; }
    *((f32x4*)&xbuf[0][xb][0] + xq) = x0;
    __syncthreads();
    if (tid < NB) {
        A1[tid][50] = (half_t)xbuf[0][tid][0];
        A1[tid][51] = (half_t)xbuf[0][tid][1];
    }
    __syncthreads();

    // ---- sequential time loop; t == TT is the head-only finale ----
    for (int t = 0; t <= TT; ++t) {
        const bool full = (t < TT);

        // phase 0: x chunk prefetch (once per KF steps; no other global access in loop)
        if (full && (t & (KF - 1)) == 0) {
            const int chunk = (t >> 5) + 1;
            if (chunk < TT / KF) {
                const f32x4 v = *(const f32x4*)(xrow + chunk * (KF * 2) + xq * 4);
                *((f32x4*)&xbuf[chunk & 1][xb][0] + xq) = v;
            }
        }

        // GEMM2 part B: k-tiles 2,3 read h2_prev (+ head W_lin rows)
        f32x4 acc2[4];
#pragma unroll
        for (int i = 0; i < 4; ++i) { f32x4 z = {0.f, 0.f, 0.f, 0.f}; acc2[i] = z; }
#pragma unroll
        for (int kt = 2; kt < 4; ++kt) {
            const f16x8 a = *(const f16x8*)&A2[cl][kt * 32 + kg];
#pragma unroll
            for (int i = 0; i < 4; ++i)
                if (i < cnt)
                    acc2[i] = __builtin_amdgcn_mfma_f32_16x16x32_f16(a, b2f[i][kt], acc2[i], 0, 0, 0);
        }

        // GEMM1: raw gates1 = [h1_prev | x | 1] @ B1  -> gsT
        if (full) {
            f32x4 acc1[4];
#pragma unroll
            for (int i = 0; i < 4; ++i) { f32x4 z = {0.f, 0.f, 0.f, 0.f}; acc1[i] = z; }
#pragma unroll
            for (int kt = 0; kt < 2; ++kt) {
                const f16x8 a = *(const f16x8*)&A1[cl][kt * 32 + kg];
#pragma unroll
                for (int i = 0; i < 4; ++i)
                    if (i < cnt)
                        acc1[i] = __builtin_amdgcn_mfma_f32_16x16x32_f16(a, b1f[i][kt], acc1[i], 0, 0, 0);
            }
#pragma unroll
            for (int i = 0; i < 4; ++i)
                if (i < cnt && gcol[i] < 200)
                    *(f32x4*)&gsT[gcol[i]][rbase] = acc1[i];
        }
        __syncthreads();   // bar1: raw gates1 visible (LDS-only drain)

        // update1: activations + c1/h1; stage x(t+1) from LDS
        if (full) {
#pragma unroll
            for (int s = 0; s < 4; ++s)
                if (uv[s]) {
                    const int b = ub[s], j = uj[s];
                    const float ri = gsT[j][b];
                    const float rf = gsT[DD + j][b];
                    const float rg = gsT[2 * DD + j][b];
                    const float ro = gsT[3 * DD + j][b];
                    const float cn = sig_f(rf) * c1r[s] + sig_f(ri) * tanh_f(rg);
                    c1r[s] = cn;
                    const half_t hn = (half_t)(sig_f(ro) * tanh_f(cn));
                    A1[b][j] = hn;
                    A2[b][j] = hn;
                }
            if (tid < NB && (t + 1) < TT) {
                const int tn = t + 1;
                const float* xs = &xbuf[(tn >> 5) & 1][tid][(tn & 31) * 2];
                A1[tid][50] = (half_t)xs[0];
                A1[tid][51] = (half_t)xs[1];
            }
        }
        __syncthreads();   // bar2: h1_new visible

        // GEMM2 part A: k-tiles 0,1 read h1_new + bias row 52
#pragma unroll
        for (int kt = 0; kt < 2; ++kt) {
            const f16x8 a = *(const f16x8*)&A2[cl][kt * 32 + kg];
#pragma unroll
            for (int i = 0; i < 4; ++i)
                if (i < cnt)
                    acc2[i] = __builtin_amdgcn_mfma_f32_16x16x32_f16(a, b2f[i][kt], acc2[i], 0, 0, 0);
        }
        // epilogue: head cols -> obuf ring; gate cols -> gsT raw
#pragma unroll
        for (int i = 0; i < 4; ++i)
            if (i < cnt) {
                if (isHead[i] && t >= 1) {
                    const int slot = (t - 1) & (KF - 1);
                    const int c    = gcol[i] - 200;
#pragma unroll
                    for (int r = 0; r < 4; ++r)
                        obuf[rbase + r][slot * 2 + c] = acc2[i][r];
                }
                if (full && gcol[i] < 200)
                    *(f32x4*)&gsT[gcol[i]][rbase] = acc2[i];
            }
        __syncthreads();   // bar3: gates2 + obuf slot visible

        // flush: once per KF steps, coalesced dwordx4 stores of 32 steps of output
        if ((t & (KF - 1)) == 0 && t >= KF) {
            const int tb = t - KF;
            const f32x4 v = *(const f32x4*)&obuf[xb][xq * 4];
            *(f32x4*)(out + ((size_t)(bg0 + xb) * TT + tb) * 2 + xq * 4) = v;
        }

        // update2: activations + c2/h2 -> A2 cols 64..113
        if (full) {
#pragma unroll
            for (int s = 0; s < 4; ++s)
                if (uv[s]) {
                    const int b = ub[s], j = uj[s];
                    const float ri = gsT[j][b];
                    const float rf = gsT[DD + j][b];
                    const float rg = gsT[2 * DD + j][b];
                    const float ro = gsT[3 * DD + j][b];
                    const float cn = sig_f(rf) * c2r[s] + sig_f(ri) * tanh_f(rg);
                    c2r[s] = cn;
                    A2[b][64 + j] = (half_t)(sig_f(ro) * tanh_f(cn));
                }
        }
        __syncthreads();   // bar4: h2_new visible for next step's part B
    }
}

extern "C" void kernel_launch(void* const* d_in, const int* in_sizes, int n_in,
                              void* d_out, int out_size, void* d_ws, size_t ws_size,
                              hipStream_t stream) {
    const float* x     = (const float*)d_in[0];
    const float* W_ih1 = (const float*)d_in[1];
    const float* W_hh1 = (const float*)d_in[2];
    const float* b_ih1 = (const float*)d_in[3];
    const float* b_hh1 = (const float*)d_in[4];
    const float* W_ih2 = (const float*)d_in[5];
    const float* W_hh2 = (const float*)d_in[6];
    const float* b_ih2 = (const float*)d_in[7];
    const float* b_hh2 = (const float*)d_in[8];
    const float* W_lin = (const float*)d_in[9];
    const float* b_lin = (const float*)d_in[10];
    float* out = (float*)d_out;

    const int B = in_sizes[0] / (TT * 2);   // 4096
    const int blocks = B / NB;              // 256

    hipLaunchKernelGGL(lstm_mfma_kernel, dim3(blocks), dim3(256), 0, stream,
                       x, W_ih1, W_hh1, b_ih1, b_hh1,
                       W_ih2, W_hh2, b_ih2, b_hh2, W_lin, b_lin, out);
}

// Round 4
// 1603.264 us; speedup vs baseline: 6.4242x; 1.4120x over previous
//
#include <hip/hip_runtime.h>
#include <stdint.h>

#define DD 50
#define TT 1024
#define NB 8             // batch rows per block (MFMA M=16, rows 8..15 zero)
#define KF 32            // x-prefetch / out-flush chunk (steps)

typedef _Float16 half_t;
typedef __attribute__((ext_vector_type(8))) _Float16 f16x8;
typedef __attribute__((ext_vector_type(4))) float    f32x4;

#define A1S 72           // K=64 (h1 | x | 1@52 | pad)
#define A2S 136          // K=128 (h1_new | 1@52 | h2_prev@64 | pad)
#define GSW 212          // gates row width (f32), row-major [b][col]

__device__ __forceinline__ float rcp_f(float x)  { return __builtin_amdgcn_rcpf(x); }
__device__ __forceinline__ float exp2_f(float x) { return __builtin_amdgcn_exp2f(x); }
__device__ __forceinline__ float sig_f(float v)  { return rcp_f(1.0f + exp2_f(-1.4426950f * v)); }
__device__ __forceinline__ float tanh_f(float v) { return 1.0f - 2.0f * rcp_f(1.0f + exp2_f(2.8853901f * v)); }

__global__ __launch_bounds__(256, 2)
void lstm_mfma_kernel(const float* __restrict__ x,
                      const float* __restrict__ W_ih1, const float* __restrict__ W_hh1,
                      const float* __restrict__ b_ih1, const float* __restrict__ b_hh1,
                      const float* __restrict__ W_ih2, const float* __restrict__ W_hh2,
                      const float* __restrict__ b_ih2, const float* __restrict__ b_hh2,
                      const float* __restrict__ W_lin, const float* __restrict__ b_lin,
                      float* __restrict__ out)
{
    const int tid   = threadIdx.x;
    const int lane  = tid & 63;
    const int w     = tid >> 6;
    const int bg0   = blockIdx.x * NB;
    const int cl    = lane & 15;          // A-row / B-col / C-col
    const int kg    = (lane >> 4) * 8;    // k base within a 32-wide k-tile
    const int rbase = (lane >> 4) * 4;    // C-row base

    __shared__ half_t A1[16][A1S];        // [h1_prev(50) | x(2) | 1@52 | 0...]
    __shared__ half_t A2[16][A2S];        // [h1_new(50) | 0 | 1@52 | 0 | h2_prev@64 | 0...]
    __shared__ float  gs1[NB][GSW];       // raw layer-1 gates
    __shared__ float  gs2[NB][GSW];       // raw layer-2 gates
    __shared__ float  obuf[NB][KF * 2];   // output ring
    __shared__ float  xbuf[2][NB][KF * 2];// x chunks, double-buffered

    // wave -> N-tile assignment over 13 tiles (cols 0..207): (4,3,3,3)
    const int cnt   = (w == 0) ? 4 : 3;
    const int tbase = (w == 0) ? 0 : 3 * w + 1;   // 0,4,7,10

    // ---- per-lane B fragments (weights + bias row 52), head folded in ----
    int   gcol[4];
    bool  isHead[4];
    f16x8 b1f[4][2];
    f16x8 b2f[4][4];

#pragma unroll
    for (int i = 0; i < 4; ++i) {
        const int g = (tbase + i) * 16 + cl;
        gcol[i] = g;
        const bool valid = (g < 200);
        isHead[i] = (g == 200) || (g == 201);
#pragma unroll
        for (int kt = 0; kt < 2; ++kt)
#pragma unroll
            for (int j = 0; j < 8; ++j) {
                const int k = kt * 32 + kg + j;
                float v = 0.f;
                if (valid) {
                    if (k < DD)          v = W_hh1[g * DD + k];
                    else if (k < DD + 2) v = W_ih1[g * 2 + (k - DD)];
                    else if (k == 52)    v = b_ih1[g] + b_hh1[g];
                }
                b1f[i][kt][j] = (half_t)v;
            }
#pragma unroll
        for (int kt = 0; kt < 4; ++kt)
#pragma unroll
            for (int j = 0; j < 8; ++j) {
                const int k = kt * 32 + kg + j;
                float v = 0.f;
                if (k < DD) {
                    if (valid) v = W_ih2[g * DD + k];
                } else if (k == 52) {
                    if (valid)          v = b_ih2[g] + b_hh2[g];
                    else if (isHead[i]) v = b_lin[g - 200];
                } else if (k >= 64 && k < 64 + DD) {
                    const int kk = k - 64;
                    if (valid)          v = W_hh2[g * DD + kk];
                    else if (isHead[i]) v = W_lin[(g - 200) * DD + kk];
                }
                b2f[i][kt][j] = (half_t)v;
            }
    }

    // ---- update mapping (static): NB*DD = 400 items over 256 threads, 2 passes ----
    int  ub[2], uj[2];
    bool uvv[2];
    float c1r[2] = {0.f, 0.f};
    float c2r[2] = {0.f, 0.f};
#pragma unroll
    for (int s = 0; s < 2; ++s) {
        const int item = tid + 256 * s;
        uvv[s] = (item < NB * DD);
        int b = item / DD;
        int j = item - b * DD;
        if (!uvv[s]) { b = 0; j = 0; }
        ub[s] = b; uj[s] = j;
    }

    const int xb = tid >> 4;      // x/out row (valid if < NB)
    const int xq = tid & 15;      // 16B quarter within 64-float chunk row
    const float* xrow = x + (size_t)(bg0 + (xb < NB ? xb : 0)) * (TT * 2);

    // ---- init: zero A, const-1 col, chunk 0, x(0) ----
    for (int idx = tid; idx < 16 * A1S; idx += 256) ((half_t*)A1)[idx] = (half_t)0.f;
    for (int idx = tid; idx < 16 * A2S; idx += 256) ((half_t*)A2)[idx] = (half_t)0.f;
    __syncthreads();
    if (tid < 16) { A1[tid][52] = (half_t)1.0f; A2[tid][52] = (half_t)1.0f; }
    if (xb < NB) {
        const f32x4 x0 = *(const f32x4*)(xrow + xq * 4);
        *((f32x4*)&xbuf[0][xb][0] + xq) = x0;
    }
    __syncthreads();
    if (tid < NB) {
        A1[tid][50] = (half_t)xbuf[0][tid][0];
        A1[tid][51] = (half_t)xbuf[0][tid][1];
    }
    __syncthreads();

    // ---- sequential time loop; t == TT is the head-only finale ----
    for (int t = 0; t <= TT; ++t) {
        const bool full = (t < TT);

        // issue next x-chunk load early (lands in regs; hidden under GEMM1)
        f32x4 xpre;
        const bool hp = full && ((t & (KF - 1)) == 0) && (((t >> 5) + 1) < TT / KF) && (xb < NB);
        if (hp) xpre = *(const f32x4*)(xrow + ((t >> 5) + 1) * (KF * 2) + xq * 4);

        // GEMM1: raw gates1 = [h1_prev | x | 1] @ B1 -> gs1
        if (full) {
            f32x4 acc1[4];
#pragma unroll
            for (int i = 0; i < 4; ++i) { f32x4 z = {0.f, 0.f, 0.f, 0.f}; acc1[i] = z; }
#pragma unroll
            for (int kt = 0; kt < 2; ++kt) {
                const f16x8 a = *(const f16x8*)&A1[cl][kt * 32 + kg];
#pragma unroll
                for (int i = 0; i < 4; ++i)
                    if (i < cnt)
                        acc1[i] = __builtin_amdgcn_mfma_f32_16x16x32_f16(a, b1f[i][kt], acc1[i], 0, 0, 0);
            }
            if (rbase < NB) {
#pragma unroll
                for (int i = 0; i < 4; ++i)
                    if (i < cnt && gcol[i] < 200) {
#pragma unroll
                        for (int r = 0; r < 4; ++r)
                            gs1[rbase + r][gcol[i]] = acc1[i][r];
                    }
            }
        }
        __syncthreads();   // bar1: gs1 visible

        // update1: activations + c1/h1 -> A1, A2[0..49]; xbuf store; stage x(t+1)
        if (full) {
#pragma unroll
            for (int s = 0; s < 2; ++s)
                if (uvv[s]) {
                    const int b = ub[s], j = uj[s];
                    const float ri = gs1[b][j];
                    const float rf = gs1[b][DD + j];
                    const float rg = gs1[b][2 * DD + j];
                    const float ro = gs1[b][3 * DD + j];
                    const float cn = sig_f(rf) * c1r[s] + sig_f(ri) * tanh_f(rg);
                    c1r[s] = cn;
                    const half_t hn = (half_t)(sig_f(ro) * tanh_f(cn));
                    A1[b][j] = hn;
                    A2[b][j] = hn;
                }
            if (hp)
                *((f32x4*)&xbuf[((t >> 5) + 1) & 1][xb][0] + xq) = xpre;
            if (tid < NB && (t + 1) < TT) {
                const int tn = t + 1;
                const float* xs = &xbuf[(tn >> 5) & 1][tid][(tn & (KF - 1)) * 2];
                A1[tid][50] = (half_t)xs[0];
                A1[tid][51] = (half_t)xs[1];
            }
        }
        __syncthreads();   // bar2: h1_new + x(t+1) visible

        // GEMM2 (all 4 k-tiles): [h1_new | 1 | h2_prev] @ B2 -> gs2 + head -> obuf
        {
            f32x4 acc2[4];
#pragma unroll
            for (int i = 0; i < 4; ++i) { f32x4 z = {0.f, 0.f, 0.f, 0.f}; acc2[i] = z; }
#pragma unroll
            for (int kt = 0; kt < 4; ++kt) {
                const f16x8 a = *(const f16x8*)&A2[cl][kt * 32 + kg];
#pragma unroll
                for (int i = 0; i < 4; ++i)
                    if (i < cnt)
                        acc2[i] = __builtin_amdgcn_mfma_f32_16x16x32_f16(a, b2f[i][kt], acc2[i], 0, 0, 0);
            }
            if (rbase < NB) {
#pragma unroll
                for (int i = 0; i < 4; ++i)
                    if (i < cnt) {
                        if (isHead[i] && t >= 1) {
                            const int slot = (t - 1) & (KF - 1);
                            const int c    = gcol[i] - 200;
#pragma unroll
                            for (int r = 0; r < 4; ++r)
                                obuf[rbase + r][slot * 2 + c] = acc2[i][r];
                        }
                        if (full && gcol[i] < 200) {
#pragma unroll
                            for (int r = 0; r < 4; ++r)
                                gs2[rbase + r][gcol[i]] = acc2[i][r];
                        }
                    }
            }
        }
        __syncthreads();   // bar3: gs2 + obuf slot visible

        // update2: activations + c2/h2 -> A2[64..]; flush obuf every KF steps
        if (full) {
#pragma unroll
            for (int s = 0; s < 2; ++s)
                if (uvv[s]) {
                    const int b = ub[s], j = uj[s];
                    const float ri = gs2[b][j];
                    const float rf = gs2[b][DD + j];
                    const float rg = gs2[b][2 * DD + j];
                    const float ro = gs2[b][3 * DD + j];
                    const float cn = sig_f(rf) * c2r[s] + sig_f(ri) * tanh_f(rg);
                    c2r[s] = cn;
                    A2[b][64 + j] = (half_t)(sig_f(ro) * tanh_f(cn));
                }
        }
        if (((t & (KF - 1)) == 0) && t >= KF && xb < NB) {
            const f32x4 v = *(const f32x4*)&obuf[xb][xq * 4];
            *(f32x4*)(out + ((size_t)(bg0 + xb) * TT + (t - KF)) * 2 + xq * 4) = v;
        }
        // no bar4: update2(t)/flush(t) and GEMM1(t+1) touch disjoint LDS
        // (gs2 vs gs1; A2[64..] vs A1); A1 inputs of GEMM1(t+1) were fixed at bar2(t).
    }
}

extern "C" void kernel_launch(void* const* d_in, const int* in_sizes, int n_in,
                              void* d_out, int out_size, void* d_ws, size_t ws_size,
                              hipStream_t stream) {
    const float* x     = (const float*)d_in[0];
    const float* W_ih1 = (const float*)d_in[1];
    const float* W_hh1 = (const float*)d_in[2];
    const float* b_ih1 = (const float*)d_in[3];
    const float* b_hh1 = (const float*)d_in[4];
    const float* W_ih2 = (const float*)d_in[5];
    const float* W_hh2 = (const float*)d_in[6];
    const float* b_ih2 = (const float*)d_in[7];
    const float* b_hh2 = (const float*)d_in[8];
    const float* W_lin = (const float*)d_in[9];
    const float* b_lin = (const float*)d_in[10];
    float* out = (float*)d_out;

    const int B = in_sizes[0] / (TT * 2);   // 4096
    const int blocks = B / NB;              // 512 -> 2 blocks/CU

    hipLaunchKernelGGL(lstm_mfma_kernel, dim3(blocks), dim3(256), 0, stream,
                       x, W_ih1, W_hh1, b_ih1, b_hh1,
                       W_ih2, W_hh2, b_ih2, b_hh2, W_lin, b_lin, out);
}

// Round 5
// 1057.257 us; speedup vs baseline: 9.7419x; 1.5164x over previous
//
#include <hip/hip_runtime.h>
#include <stdint.h>

#define DD 50
#define TT 1024
#define NB 16            // batch rows per block = MFMA M (full tile)
#define KF 32            // x-prefetch / out-flush chunk (steps)

typedef _Float16 half_t;
typedef __attribute__((ext_vector_type(8))) _Float16 f16x8;
typedef __attribute__((ext_vector_type(4))) float    f32x4;

#define A1S 72           // K=64: h1(50) | x(2) | 1@52 | pad, halves
#define A2S 136          // K=128: h1(50) | 1@52 | h2@64(50) | pad
#define OBW 68           // obuf row stride (f32): 64 + 4 pad (bank stride 4)

__device__ __forceinline__ float rcp_f(float x)  { return __builtin_amdgcn_rcpf(x); }
__device__ __forceinline__ float exp2_f(float x) { return __builtin_amdgcn_exp2f(x); }
__device__ __forceinline__ float sig_f(float v)  { return rcp_f(1.0f + exp2_f(-1.4426950f * v)); }
__device__ __forceinline__ float tanh_f(float v) { return 1.0f - 2.0f * rcp_f(1.0f + exp2_f(2.8853901f * v)); }

// Gate columns interleaved: col' = 4*jj + gate (gate: 0=i 1=f 2=g 3=o).
// MFMA called with SWAPPED operands (weights first): C[m=col'][n=batch],
// m = (lane>>4)*4 + reg, n = lane&15  =>  lane (cl,g2) holds, per tile,
// acc[r] = gate r of (b=cl, jj=4*tile+g2): the full cell update is per-lane.

__global__ __launch_bounds__(512, 2)
void lstm_mfma_kernel(const float* __restrict__ x,
                      const float* __restrict__ W_ih1, const float* __restrict__ W_hh1,
                      const float* __restrict__ b_ih1, const float* __restrict__ b_hh1,
                      const float* __restrict__ W_ih2, const float* __restrict__ W_hh2,
                      const float* __restrict__ b_ih2, const float* __restrict__ b_hh2,
                      const float* __restrict__ W_lin, const float* __restrict__ b_lin,
                      float* __restrict__ out)
{
    const int tid  = threadIdx.x;
    const int lane = tid & 63;
    const int w    = tid >> 6;           // 0..7
    const int bg0  = blockIdx.x * NB;
    const int cl   = lane & 15;          // batch row (n) / frag index
    const int g2   = lane >> 4;          // k-group; C: jj offset within tile

    __shared__ half_t A1[2][NB][A1S];    // parity-double-buffered
    __shared__ half_t A2[2][NB][A2S];
    __shared__ float  obuf[2][NB][OBW];  // out ring, 32-step double buffer
    __shared__ float  xbuf[2][NB][KF*2]; // x chunks, 32-step double buffer

    // 13 N-tiles over 8 waves: waves 0-4 get 2, waves 5-7 get 1 (tile 12 = head on wave 7)
    const int cnt   = (w < 5) ? 2 : 1;
    const int tbase = (w < 5) ? 2 * w : 5 + w;

    // ---- B fragments: col' = tile*16 + cl; col'<200: jj=col'>>2, gate=col'&3 ----
    f16x8 b1f[2][2];
    f16x8 b2f[2][4];
#pragma unroll
    for (int i = 0; i < 2; ++i) {
        const int  colp  = (tbase + i) * 16 + cl;
        const bool valid = (colp < 200) && (i < cnt);
        const bool headB = ((colp == 200) || (colp == 201)) && (i < cnt);
        const int  g     = (colp & 3) * DD + (colp >> 2);   // original gate row
#pragma unroll
        for (int kt = 0; kt < 2; ++kt)
#pragma unroll
            for (int j = 0; j < 8; ++j) {
                const int k = kt * 32 + g2 * 8 + j;
                float v = 0.f;
                if (valid) {
                    if (k < DD)          v = W_hh1[g * DD + k];
                    else if (k < DD + 2) v = W_ih1[g * 2 + (k - DD)];
                    else if (k == 52)    v = b_ih1[g] + b_hh1[g];
                }
                b1f[i][kt][j] = (half_t)v;
            }
#pragma unroll
        for (int kt = 0; kt < 4; ++kt)
#pragma unroll
            for (int j = 0; j < 8; ++j) {
                const int k = kt * 32 + g2 * 8 + j;
                float v = 0.f;
                if (k < DD) {
                    if (valid) v = W_ih2[g * DD + k];
                } else if (k == 52) {
                    if (valid)          v = b_ih2[g] + b_hh2[g];
                    else if (headB)     v = b_lin[colp - 200];
                } else if (k >= 64 && k < 64 + DD) {
                    if (valid)          v = W_hh2[g * DD + (k - 64)];
                    else if (headB)     v = W_lin[(colp - 200) * DD + (k - 64)];
                }
                b2f[i][kt][j] = (half_t)v;
            }
    }

    // ---- init: zero A (h=0, pads=0), xbuf chunk 0, x(0), const-1 cols ----
    for (int idx = tid; idx < 2 * NB * A1S; idx += 512) ((half_t*)A1)[idx] = (half_t)0.f;
    for (int idx = tid; idx < 2 * NB * A2S; idx += 512) ((half_t*)A2)[idx] = (half_t)0.f;
    if (tid >= 256) {
        const int idx = tid - 256, xr = idx >> 4, xq = idx & 15;
        const f32x4 v = *(const f32x4*)(x + (size_t)(bg0 + xr) * (TT * 2) + xq * 4);
        *(f32x4*)&xbuf[0][xr][xq * 4] = v;
    }
    __syncthreads();
    if (tid < NB) {
        A1[0][tid][50] = (half_t)xbuf[0][tid][0];
        A1[0][tid][51] = (half_t)xbuf[0][tid][1];
        A1[0][tid][52] = (half_t)1.0f; A1[1][tid][52] = (half_t)1.0f;
        A2[0][tid][52] = (half_t)1.0f; A2[1][tid][52] = (half_t)1.0f;
    }
    __syncthreads();

    float c1r[2] = {0.f, 0.f};
    float c2r[2] = {0.f, 0.f};

    // ---- time loop; t == TT is head-only finale ----
    for (int t = 0; t <= TT; ++t) {
        const int  p    = t & 1;
        const int  np   = p ^ 1;
        const bool full = (t < TT);

        // out flush: waves 4-7, once per 32 steps, reads settled obuf buffer
        if (((t & 31) == 1) && (t >= 33) && (tid >= 256)) {
            const int fr = (tid - 256) >> 4, fq = (tid - 256) & 15;
            const f32x4 v = *(const f32x4*)&obuf[((t - 33) >> 5) & 1][fr][fq * 4];
            *(f32x4*)(out + (size_t)(bg0 + fr) * (TT * 2) + (t - 33) * 2 + fq * 4) = v;
        }
        // x chunk prefetch into regs (waves 4-7); LDS store later this segment
        f32x4 xpre; bool hp = false;
        if (full && ((t & 31) == 0) && (tid >= 256)) {
            const int chunk = (t >> 5) + 1;
            if (chunk < TT / KF) {
                hp = true;
                const int idx = tid - 256, xr = idx >> 4, xq = idx & 15;
                xpre = *(const f32x4*)(x + (size_t)(bg0 + xr) * (TT * 2) + chunk * (KF * 2) + xq * 4);
            }
        }

        f32x4 acc1[2], acc2[2];
        // GEMM1: raw gates1, operands swapped (weights first)
        if (full) {
#pragma unroll
            for (int i = 0; i < 2; ++i) { f32x4 z = {0.f,0.f,0.f,0.f}; acc1[i] = z; }
#pragma unroll
            for (int kt = 0; kt < 2; ++kt) {
                const f16x8 a = *(const f16x8*)&A1[p][cl][kt * 32 + g2 * 8];
#pragma unroll
                for (int i = 0; i < 2; ++i)
                    if (i < cnt)
                        acc1[i] = __builtin_amdgcn_mfma_f32_16x16x32_f16(b1f[i][kt], a, acc1[i], 0, 0, 0);
            }
        }
        // GEMM2 k-tiles 2,3 (h2_prev region, stable since last bar_B) — issue early
#pragma unroll
        for (int i = 0; i < 2; ++i) { f32x4 z = {0.f,0.f,0.f,0.f}; acc2[i] = z; }
#pragma unroll
        for (int kt = 2; kt < 4; ++kt) {
            const f16x8 a = *(const f16x8*)&A2[p][cl][kt * 32 + g2 * 8];
#pragma unroll
            for (int i = 0; i < 2; ++i)
                if (i < cnt)
                    acc2[i] = __builtin_amdgcn_mfma_f32_16x16x32_f16(b2f[i][kt], a, acc2[i], 0, 0, 0);
        }
        // update1: per-lane, in-register; h1 -> A1[np] (next GEMM1) and A2[p] (this GEMM2)
        if (full) {
#pragma unroll
            for (int i = 0; i < 2; ++i) {
                const int jj = (tbase + i) * 4 + g2;
                if (i < cnt && jj < DD) {
                    const float pi = sig_f(acc1[i][0]);
                    const float pf = sig_f(acc1[i][1]);
                    const float pg = tanh_f(acc1[i][2]);
                    const float po = sig_f(acc1[i][3]);
                    const float cn = pf * c1r[i] + pi * pg;
                    c1r[i] = cn;
                    const half_t h = (half_t)(po * tanh_f(cn));
                    A1[np][cl][jj] = h;
                    A2[p][cl][jj]  = h;
                }
            }
            if (tid >= 384 && tid < 384 + NB && (t + 1) < TT) {   // wave 6: stage x(t+1)
                const int b = tid - 384, tn = t + 1;
                const float* xs = &xbuf[(tn >> 5) & 1][b][(tn & 31) * 2];
                A1[np][b][50] = (half_t)xs[0];
                A1[np][b][51] = (half_t)xs[1];
            }
            if (hp) {
                const int idx = tid - 256, xr = idx >> 4, xq = idx & 15;
                *(f32x4*)&xbuf[((t >> 5) + 1) & 1][xr][xq * 4] = xpre;
            }
        }
        __syncthreads();   // bar_A: h1(t) visible in A2[p]

        // GEMM2 k-tiles 0,1 (h1_new + bias@52)
#pragma unroll
        for (int kt = 0; kt < 2; ++kt) {
            const f16x8 a = *(const f16x8*)&A2[p][cl][kt * 32 + g2 * 8];
#pragma unroll
            for (int i = 0; i < 2; ++i)
                if (i < cnt)
                    acc2[i] = __builtin_amdgcn_mfma_f32_16x16x32_f16(b2f[i][kt], a, acc2[i], 0, 0, 0);
        }
        // update2 + head
#pragma unroll
        for (int i = 0; i < 2; ++i) {
            const int tile = tbase + i;
            const int jj   = tile * 4 + g2;
            if (full && i < cnt && jj < DD) {
                const float pi = sig_f(acc2[i][0]);
                const float pf = sig_f(acc2[i][1]);
                const float pg = tanh_f(acc2[i][2]);
                const float po = sig_f(acc2[i][3]);
                const float cn = pf * c2r[i] + pi * pg;
                c2r[i] = cn;
                A2[np][cl][64 + jj] = (half_t)(po * tanh_f(cn));
            }
            if (i < cnt && tile == 12 && g2 == 2 && t >= 1) {     // cols 200,201 = out(t-1)
                const int s = t - 1;
                obuf[(s >> 5) & 1][cl][(s & 31) * 2 + 0] = acc2[i][0];
                obuf[(s >> 5) & 1][cl][(s & 31) * 2 + 1] = acc2[i][1];
            }
        }
        __syncthreads();   // bar_B: h2(t) visible for next step
    }

    // final flush: outs TT-32 .. TT-1 (buffer ((TT-32)>>5)&1 = 1)
    if (tid >= 256) {
        const int fr = (tid - 256) >> 4, fq = (tid - 256) & 15;
        const f32x4 v = *(const f32x4*)&obuf[1][fr][fq * 4];
        *(f32x4*)(out + (size_t)(bg0 + fr) * (TT * 2) + (TT - KF) * 2 + fq * 4) = v;
    }
}

extern "C" void kernel_launch(void* const* d_in, const int* in_sizes, int n_in,
                              void* d_out, int out_size, void* d_ws, size_t ws_size,
                              hipStream_t stream) {
    const float* x     = (const float*)d_in[0];
    const float* W_ih1 = (const float*)d_in[1];
    const float* W_hh1 = (const float*)d_in[2];
    const float* b_ih1 = (const float*)d_in[3];
    const float* b_hh1 = (const float*)d_in[4];
    const float* W_ih2 = (const float*)d_in[5];
    const float* W_hh2 = (const float*)d_in[6];
    const float* b_ih2 = (const float*)d_in[7];
    const float* b_hh2 = (const float*)d_in[8];
    const float* W_lin = (const float*)d_in[9];
    const float* b_lin = (const float*)d_in[10];
    float* out = (float*)d_out;

    const int B = in_sizes[0] / (TT * 2);   // 4096
    const int blocks = B / NB;              // 256

    hipLaunchKernelGGL(lstm_mfma_kernel, dim3(blocks), dim3(512), 0, stream,
                       x, W_ih1, W_hh1, b_ih1, b_hh1,
                       W_ih2, W_hh2, b_ih2, b_hh2, W_lin, b_lin, out);
}

// Round 6
// 1028.362 us; speedup vs baseline: 10.0157x; 1.0281x over previous
//
#include <hip/hip_runtime.h>
#include <stdint.h>

#define DD 50
#define TT 1024
#define NB 16            // batch rows per block = MFMA M (full tile)
#define KF 32            // x-prefetch / out-flush chunk (steps)

typedef _Float16 half_t;
typedef __attribute__((ext_vector_type(8))) _Float16 f16x8;
typedef __attribute__((ext_vector_type(4))) float    f32x4;

#define A1S 72           // K=64: h1(50) | x(2) | 1@52 | pad
#define A2S 136          // K=128: h1(50) | 1@52 | h2@64(50) | pad
#define OBW 68           // obuf row stride (f32)

__device__ __forceinline__ float rcp_f(float x)  { return __builtin_amdgcn_rcpf(x); }
__device__ __forceinline__ float exp2_f(float x) { return __builtin_amdgcn_exp2f(x); }
__device__ __forceinline__ float sig_f(float v)  { return rcp_f(1.0f + exp2_f(-1.4426950f * v)); }
__device__ __forceinline__ float tanh_f(float v) { return 1.0f - 2.0f * rcp_f(1.0f + exp2_f(2.8853901f * v)); }

// Gate columns interleaved: col' = 4*jj + gate (0=i 1=f 2=g 3=o). MFMA with
// swapped operands (weights first): C[m=col'][n=batch], m=(lane>>4)*4+reg,
// n=lane&15 => lane (cl,g2) holds acc[r] = gate r of (b=cl, jj=4*tile+g2):
// cell update is per-lane, in-register.
//
// ONE barrier per step: within iteration I (parity p=I&1), compute
//   GEMM2(I)   from A2[p] (h1(I), h2(I-1))   -> update2(I)  -> h2(I)  -> A2[np]
//   GEMM1(I+1) from A1[p] (h1(I), x(I+1))    -> update1(I+1)-> h1(I+1)-> A1[np],A2[np]
// then barrier; next iteration reads [np]. Head (cols 200,201, zero weights in
// kt0/1 except bias@52) yields out(I-1) from GEMM2(I).

__global__ __launch_bounds__(512, 2)
void lstm_mfma_kernel(const float* __restrict__ x,
                      const float* __restrict__ W_ih1, const float* __restrict__ W_hh1,
                      const float* __restrict__ b_ih1, const float* __restrict__ b_hh1,
                      const float* __restrict__ W_ih2, const float* __restrict__ W_hh2,
                      const float* __restrict__ b_ih2, const float* __restrict__ b_hh2,
                      const float* __restrict__ W_lin, const float* __restrict__ b_lin,
                      float* __restrict__ out)
{
    const int tid  = threadIdx.x;
    const int lane = tid & 63;
    const int w    = tid >> 6;           // 0..7
    const int bg0  = blockIdx.x * NB;
    const int cl   = lane & 15;          // batch row (n)
    const int g2   = lane >> 4;          // k-group / jj offset within tile

    __shared__ half_t A1[2][NB][A1S];
    __shared__ half_t A2[2][NB][A2S];
    __shared__ float  obuf[2][NB][OBW];
    __shared__ float  xbuf[2][NB][KF*2];

    // 13 N-tiles over 8 waves: waves 0-4 two tiles, 5-7 one (tile 12 = head, wave 7)
    const int cnt   = (w < 5) ? 2 : 1;
    const int tbase = (w < 5) ? 2 * w : 5 + w;

    // ---- B fragments ----
    f16x8 b1f[2][2];
    f16x8 b2f[2][4];
#pragma unroll
    for (int i = 0; i < 2; ++i) {
        const int  colp  = (tbase + i) * 16 + cl;
        const bool valid = (colp < 200) && (i < cnt);
        const bool headB = ((colp == 200) || (colp == 201)) && (i < cnt);
        const int  g     = (colp & 3) * DD + (colp >> 2);
#pragma unroll
        for (int kt = 0; kt < 2; ++kt)
#pragma unroll
            for (int j = 0; j < 8; ++j) {
                const int k = kt * 32 + g2 * 8 + j;
                float v = 0.f;
                if (valid) {
                    if (k < DD)          v = W_hh1[g * DD + k];
                    else if (k < DD + 2) v = W_ih1[g * 2 + (k - DD)];
                    else if (k == 52)    v = b_ih1[g] + b_hh1[g];
                }
                b1f[i][kt][j] = (half_t)v;
            }
#pragma unroll
        for (int kt = 0; kt < 4; ++kt)
#pragma unroll
            for (int j = 0; j < 8; ++j) {
                const int k = kt * 32 + g2 * 8 + j;
                float v = 0.f;
                if (k < DD) {
                    if (valid) v = W_ih2[g * DD + k];
                } else if (k == 52) {
                    if (valid)          v = b_ih2[g] + b_hh2[g];
                    else if (headB)     v = b_lin[colp - 200];
                } else if (k >= 64 && k < 64 + DD) {
                    if (valid)          v = W_hh2[g * DD + (k - 64)];
                    else if (headB)     v = W_lin[(colp - 200) * DD + (k - 64)];
                }
                b2f[i][kt][j] = (half_t)v;
            }
    }

    // ---- init: zero A both parities, const-1@52, xbuf chunk 0, x(0)->A1[1] ----
    for (int idx = tid; idx < 2 * NB * A1S; idx += 512) ((half_t*)A1)[idx] = (half_t)0.f;
    for (int idx = tid; idx < 2 * NB * A2S; idx += 512) ((half_t*)A2)[idx] = (half_t)0.f;
    if (tid >= 256) {
        const int idx = tid - 256, xr = idx >> 4, xq = idx & 15;
        const f32x4 v = *(const f32x4*)(x + (size_t)(bg0 + xr) * (TT * 2) + xq * 4);
        *(f32x4*)&xbuf[0][xr][xq * 4] = v;
    }
    __syncthreads();
    if (tid < NB) {
        A1[0][tid][52] = (half_t)1.0f; A1[1][tid][52] = (half_t)1.0f;
        A2[0][tid][52] = (half_t)1.0f; A2[1][tid][52] = (half_t)1.0f;
        A1[1][tid][50] = (half_t)xbuf[0][tid][0];    // x(0), parity of I=-1
        A1[1][tid][51] = (half_t)xbuf[0][tid][1];
    }
    __syncthreads();

    float c1r[2] = {0.f, 0.f};
    float c2r[2] = {0.f, 0.f};

    // ---- pipelined loop: I = -1 (prologue) .. TT (head finale), ONE barrier each ----
    for (int I = -1; I <= TT; ++I) {
        const int p  = I & 1;
        const int np = p ^ 1;

        // out flush: once per 32 steps (buffer settled >=1 barrier ago)
        if (((I & 31) == 1) && I >= 33 && tid >= 256) {
            const int fr = (tid - 256) >> 4, fq = (tid - 256) & 15;
            const f32x4 v = *(const f32x4*)&obuf[((I - 33) >> 5) & 1][fr][fq * 4];
            *(f32x4*)(out + (size_t)(bg0 + fr) * (TT * 2) + (I - 33) * 2 + fq * 4) = v;
        }
        // x chunk prefetch into regs (stored to xbuf later this interval)
        f32x4 xpre; bool hp = false;
        if (I >= 0 && ((I & 31) == 0) && tid >= 256) {
            const int chunk = (I >> 5) + 1;
            if (chunk < TT / KF) {
                hp = true;
                const int idx = tid - 256, xr = idx >> 4, xq = idx & 15;
                xpre = *(const f32x4*)(x + (size_t)(bg0 + xr) * (TT * 2) + chunk * (KF * 2) + xq * 4);
            }
        }

        // GEMM2(I): all 4 k-tiles from A2[p]
        f32x4 acc2[2];
        if (I >= 0) {
#pragma unroll
            for (int i = 0; i < 2; ++i) { f32x4 z = {0.f,0.f,0.f,0.f}; acc2[i] = z; }
#pragma unroll
            for (int kt = 0; kt < 4; ++kt) {
                const f16x8 a = *(const f16x8*)&A2[p][cl][kt * 32 + g2 * 8];
#pragma unroll
                for (int i = 0; i < 2; ++i)
                    if (i < cnt)
                        acc2[i] = __builtin_amdgcn_mfma_f32_16x16x32_f16(b2f[i][kt], a, acc2[i], 0, 0, 0);
            }
        }
        // GEMM1(I+1): 2 k-tiles from A1[p] (h1(I), x(I+1), 1@52)
        f32x4 acc1[2];
        if (I < TT) {
#pragma unroll
            for (int i = 0; i < 2; ++i) { f32x4 z = {0.f,0.f,0.f,0.f}; acc1[i] = z; }
#pragma unroll
            for (int kt = 0; kt < 2; ++kt) {
                const f16x8 a = *(const f16x8*)&A1[p][cl][kt * 32 + g2 * 8];
#pragma unroll
                for (int i = 0; i < 2; ++i)
                    if (i < cnt)
                        acc1[i] = __builtin_amdgcn_mfma_f32_16x16x32_f16(b1f[i][kt], a, acc1[i], 0, 0, 0);
            }
        }

        // update2(I): per-lane -> h2(I) -> A2[np][64+jj]; head -> obuf
        if (I >= 0) {
            if (I < TT) {
#pragma unroll
                for (int i = 0; i < 2; ++i) {
                    const int jj = (tbase + i) * 4 + g2;
                    if (i < cnt && jj < DD) {
                        const float pi = sig_f(acc2[i][0]);
                        const float pf = sig_f(acc2[i][1]);
                        const float pg = tanh_f(acc2[i][2]);
                        const float po = sig_f(acc2[i][3]);
                        const float cn = pf * c2r[i] + pi * pg;
                        c2r[i] = cn;
                        A2[np][cl][64 + jj] = (half_t)(po * tanh_f(cn));
                    }
                }
            }
            if (w == 7 && g2 == 2 && I >= 1) {       // cols 200,201 -> out(I-1)
                const int s = I - 1;
                obuf[(s >> 5) & 1][cl][(s & 31) * 2 + 0] = acc2[0][0];
                obuf[(s >> 5) & 1][cl][(s & 31) * 2 + 1] = acc2[0][1];
            }
        }
        // update1(I+1): per-lane -> h1(I+1) -> A1[np], A2[np]
        if (I < TT) {
#pragma unroll
            for (int i = 0; i < 2; ++i) {
                const int jj = (tbase + i) * 4 + g2;
                if (i < cnt && jj < DD) {
                    const float pi = sig_f(acc1[i][0]);
                    const float pf = sig_f(acc1[i][1]);
                    const float pg = tanh_f(acc1[i][2]);
                    const float po = sig_f(acc1[i][3]);
                    const float cn = pf * c1r[i] + pi * pg;
                    c1r[i] = cn;
                    const half_t h = (half_t)(po * tanh_f(cn));
                    A1[np][cl][jj] = h;
                    A2[np][cl][jj] = h;
                }
            }
            // x-stage: wave 7, g2==3 lanes (no update items there): x(I+2) -> A1[np]
            if (w == 7 && g2 == 3 && (I + 2) < TT) {
                const int r = lane - 48, tn = I + 2;
                const float* xs = &xbuf[(tn >> 5) & 1][r][(tn & 31) * 2];
                A1[np][r][50] = (half_t)xs[0];
                A1[np][r][51] = (half_t)xs[1];
            }
            if (hp) {
                const int idx = tid - 256, xr = idx >> 4, xq = idx & 15;
                *(f32x4*)&xbuf[(((I >> 5) + 1) & 1)][xr][xq * 4] = xpre;
            }
        }
        __syncthreads();   // the ONE barrier: h1(I+1), h2(I) published
    }

    // final flush: steps TT-32..TT-1 live in obuf[1]
    if (tid >= 256) {
        const int fr = (tid - 256) >> 4, fq = (tid - 256) & 15;
        const f32x4 v = *(const f32x4*)&obuf[1][fr][fq * 4];
        *(f32x4*)(out + (size_t)(bg0 + fr) * (TT * 2) + (TT - KF) * 2 + fq * 4) = v;
    }
}

extern "C" void kernel_launch(void* const* d_in, const int* in_sizes, int n_in,
                              void* d_out, int out_size, void* d_ws, size_t ws_size,
                              hipStream_t stream) {
    const float* x     = (const float*)d_in[0];
    const float* W_ih1 = (const float*)d_in[1];
    const float* W_hh1 = (const float*)d_in[2];
    const float* b_ih1 = (const float*)d_in[3];
    const float* b_hh1 = (const float*)d_in[4];
    const float* W_ih2 = (const float*)d_in[5];
    const float* W_hh2 = (const float*)d_in[6];
    const float* b_ih2 = (const float*)d_in[7];
    const float* b_hh2 = (const float*)d_in[8];
    const float* W_lin = (const float*)d_in[9];
    const float* b_lin = (const float*)d_in[10];
    float* out = (float*)d_out;

    const int B = in_sizes[0] / (TT * 2);   // 4096
    const int blocks = B / NB;              // 256

    hipLaunchKernelGGL(lstm_mfma_kernel, dim3(blocks), dim3(512), 0, stream,
                       x, W_ih1, W_hh1, b_ih1, b_hh1,
                       W_ih2, W_hh2, b_ih2, b_hh2, W_lin, b_lin, out);
}

// Round 7
// 890.044 us; speedup vs baseline: 11.5722x; 1.1554x over previous
//
#include <hip/hip_runtime.h>
#include <stdint.h>

#define DD 50
#define TT 1024
#define NB 16            // batch rows per block = MFMA M (full tile)
#define KF 32            // x-prefetch / out-flush chunk (steps)

typedef _Float16 half_t;
typedef __attribute__((ext_vector_type(8))) _Float16 f16x8;
typedef __attribute__((ext_vector_type(4))) float    f32x4;

#define AHS 72           // K=64: h1(50) | x(2) | 1@52 | pad — 144B rows (16B aligned)
#define A2S 72           // K=64: h2(50) | pad
#define OBW 68           // obuf row stride (f32)

__device__ __forceinline__ float rcp_f(float x)  { return __builtin_amdgcn_rcpf(x); }
__device__ __forceinline__ float exp2_f(float x) { return __builtin_amdgcn_exp2f(x); }

// Fused LSTM cell update, rcp-merged:
//   sig(i)*tanh(g) = (b-1) / [(1+a)(1+b)],  a=e^-i, b=e^{2g}
//   h = sig(o)*tanh(cn) = (e-1) / [(1+o_)(1+e)], o_=e^-o, e=e^{2cn}
// 5 exp2 + 3 rcp per cell (was 5+5).
__device__ __forceinline__ float cell_update(const f32x4 acc, float& c) {
    const float a   = exp2_f(-1.4426950f * acc[0]);
    const float b   = exp2_f( 2.8853901f * acc[2]);
    const float t   = 1.0f + a;
    const float pig = (b - 1.0f) * rcp_f(t + t * b);
    const float pf  = rcp_f(1.0f + exp2_f(-1.4426950f * acc[1]));
    const float cn  = pf * c + pig;
    c = cn;
    const float o_  = exp2_f(-1.4426950f * acc[3]);
    const float e   = exp2_f( 2.8853901f * cn);
    const float t2  = 1.0f + o_;
    return (e - 1.0f) * rcp_f(t2 + t2 * e);
}

// Gate columns interleaved: col' = 4*jj + gate (0=i 1=f 2=g 3=o). MFMA with
// swapped operands (weights first): C[m=col'][n=batch], m=(lane>>4)*4+reg,
// n=lane&15 => lane (cl,g2) holds acc[r] = gate r of (b=cl, jj=4*tile+g2).
//
// Shared-K trick: AH = [h1(50)|x(2)|1@52] (K=64) is the A operand for BOTH
// GEMM1 (B1: W_hh1|W_ih1|bias1) and GEMM2's first half (B2 kt0/1:
// W_ih2|0,0|bias2 — x rows are zero). A2 = [h2(50)] (K=64) is GEMM2's
// second half (B2 kt2/3: W_hh2 / W_lin for head cols). One barrier per step.

__global__ __launch_bounds__(512, 2)
void lstm_mfma_kernel(const float* __restrict__ x,
                      const float* __restrict__ W_ih1, const float* __restrict__ W_hh1,
                      const float* __restrict__ b_ih1, const float* __restrict__ b_hh1,
                      const float* __restrict__ W_ih2, const float* __restrict__ W_hh2,
                      const float* __restrict__ b_ih2, const float* __restrict__ b_hh2,
                      const float* __restrict__ W_lin, const float* __restrict__ b_lin,
                      float* __restrict__ out)
{
    const int tid  = threadIdx.x;
    const int lane = tid & 63;
    const int w    = tid >> 6;           // 0..7
    const int bg0  = blockIdx.x * NB;
    const int cl   = lane & 15;          // batch row (n)
    const int g2   = lane >> 4;          // k-group / jj offset within tile

    __shared__ half_t AH[2][NB][AHS];    // parity double-buffered
    __shared__ half_t A2[2][NB][A2S];
    __shared__ float  obuf[2][NB][OBW];
    __shared__ float  xbuf[2][NB][KF*2];

    // 13 N-tiles over 8 waves: waves 0-4 two tiles, 5-7 one (tile 12 = head, wave 7)
    const int cnt   = (w < 5) ? 2 : 1;
    const int tbase = (w < 5) ? 2 * w : 5 + w;

    // ---- B fragments ----
    f16x8 b1f[2][2];
    f16x8 b2f[2][4];
#pragma unroll
    for (int i = 0; i < 2; ++i) {
        const int  colp  = (tbase + i) * 16 + cl;
        const bool valid = (colp < 200) && (i < cnt);
        const bool headB = ((colp == 200) || (colp == 201)) && (i < cnt);
        const int  g     = (colp & 3) * DD + (colp >> 2);
        // B1 over AH-k: W_hh1 | W_ih1@50,51 | bias1@52
#pragma unroll
        for (int kt = 0; kt < 2; ++kt)
#pragma unroll
            for (int j = 0; j < 8; ++j) {
                const int k = kt * 32 + g2 * 8 + j;
                float v = 0.f;
                if (valid) {
                    if (k < DD)          v = W_hh1[g * DD + k];
                    else if (k < DD + 2) v = W_ih1[g * 2 + (k - DD)];
                    else if (k == 52)    v = b_ih1[g] + b_hh1[g];
                }
                b1f[i][kt][j] = (half_t)v;
            }
        // B2 kt0/1 over AH-k: W_ih2 | zeros@50,51 | bias2@52 (head: b_lin@52)
#pragma unroll
        for (int kt = 0; kt < 2; ++kt)
#pragma unroll
            for (int j = 0; j < 8; ++j) {
                const int k = kt * 32 + g2 * 8 + j;
                float v = 0.f;
                if (k < DD) {
                    if (valid) v = W_ih2[g * DD + k];
                } else if (k == 52) {
                    if (valid)      v = b_ih2[g] + b_hh2[g];
                    else if (headB) v = b_lin[colp - 200];
                }
                b2f[i][kt][j] = (half_t)v;
            }
        // B2 kt2/3 over A2-k (h2 at k'=0..49): W_hh2 (head: W_lin)
#pragma unroll
        for (int kt = 2; kt < 4; ++kt)
#pragma unroll
            for (int j = 0; j < 8; ++j) {
                const int kk = (kt - 2) * 32 + g2 * 8 + j;
                float v = 0.f;
                if (kk < DD) {
                    if (valid)      v = W_hh2[g * DD + kk];
                    else if (headB) v = W_lin[(colp - 200) * DD + kk];
                }
                b2f[i][kt][j] = (half_t)v;
            }
    }

    // ---- init: zero buffers, const-1@52 both parities, xbuf chunk 0, x(0)->AH[1] ----
    for (int idx = tid; idx < 2 * NB * AHS; idx += 512) ((half_t*)AH)[idx] = (half_t)0.f;
    for (int idx = tid; idx < 2 * NB * A2S; idx += 512) ((half_t*)A2)[idx] = (half_t)0.f;
    if (tid >= 256) {
        const int idx = tid - 256, xr = idx >> 4, xq = idx & 15;
        const f32x4 v = *(const f32x4*)(x + (size_t)(bg0 + xr) * (TT * 2) + xq * 4);
        *(f32x4*)&xbuf[0][xr][xq * 4] = v;
    }
    __syncthreads();
    if (tid < NB) {
        AH[0][tid][52] = (half_t)1.0f; AH[1][tid][52] = (half_t)1.0f;
        AH[1][tid][50] = (half_t)xbuf[0][tid][0];    // x(0), parity of I=-1
        AH[1][tid][51] = (half_t)xbuf[0][tid][1];
    }
    __syncthreads();

    float c1r[2] = {0.f, 0.f};
    float c2r[2] = {0.f, 0.f};

    // ---- pipelined loop: I = -1 (prologue) .. TT (head finale), ONE barrier each ----
    for (int I = -1; I <= TT; ++I) {
        const int p  = I & 1;
        const int np = p ^ 1;

        // out flush: once per 32 steps (buffer settled >=1 barrier ago)
        if (((I & 31) == 1) && I >= 33 && tid >= 256) {
            const int fr = (tid - 256) >> 4, fq = (tid - 256) & 15;
            const f32x4 v = *(const f32x4*)&obuf[((I - 33) >> 5) & 1][fr][fq * 4];
            *(f32x4*)(out + (size_t)(bg0 + fr) * (TT * 2) + (I - 33) * 2 + fq * 4) = v;
        }
        // x chunk prefetch into regs (stored to xbuf later this interval)
        f32x4 xpre; bool hp = false;
        if (I >= 0 && ((I & 31) == 0) && tid >= 256) {
            const int chunk = (I >> 5) + 1;
            if (chunk < TT / KF) {
                hp = true;
                const int idx = tid - 256, xr = idx >> 4, xq = idx & 15;
                xpre = *(const f32x4*)(x + (size_t)(bg0 + xr) * (TT * 2) + chunk * (KF * 2) + xq * 4);
            }
        }

        // shared A-fragment loads (4 x ds_read_b128; AH feeds BOTH GEMMs)
        const f16x8 a0 = *(const f16x8*)&AH[p][cl][g2 * 8];
        const f16x8 a1 = *(const f16x8*)&AH[p][cl][32 + g2 * 8];
        const f16x8 h0 = *(const f16x8*)&A2[p][cl][g2 * 8];
        const f16x8 h1 = *(const f16x8*)&A2[p][cl][32 + g2 * 8];

        // GEMM2(I): kt2/3 on h2(I-1), kt0/1 on [h1(I)|x|1]
        f32x4 acc2[2];
        if (I >= 0) {
#pragma unroll
            for (int i = 0; i < 2; ++i) {
                f32x4 z = {0.f,0.f,0.f,0.f};
                if (i < cnt) {
                    z = __builtin_amdgcn_mfma_f32_16x16x32_f16(b2f[i][2], h0, z, 0, 0, 0);
                    z = __builtin_amdgcn_mfma_f32_16x16x32_f16(b2f[i][3], h1, z, 0, 0, 0);
                    z = __builtin_amdgcn_mfma_f32_16x16x32_f16(b2f[i][0], a0, z, 0, 0, 0);
                    z = __builtin_amdgcn_mfma_f32_16x16x32_f16(b2f[i][1], a1, z, 0, 0, 0);
                }
                acc2[i] = z;
            }
        }
        // GEMM1(I+1): [h1(I)|x(I+1)|1] @ B1
        f32x4 acc1[2];
        if (I < TT) {
#pragma unroll
            for (int i = 0; i < 2; ++i) {
                f32x4 z = {0.f,0.f,0.f,0.f};
                if (i < cnt) {
                    z = __builtin_amdgcn_mfma_f32_16x16x32_f16(b1f[i][0], a0, z, 0, 0, 0);
                    z = __builtin_amdgcn_mfma_f32_16x16x32_f16(b1f[i][1], a1, z, 0, 0, 0);
                }
                acc1[i] = z;
            }
        }

        // update2(I): per-lane -> h2(I) -> A2[np]; head -> obuf
        if (I >= 0) {
            if (I < TT) {
#pragma unroll
                for (int i = 0; i < 2; ++i) {
                    const int jj = (tbase + i) * 4 + g2;
                    if (i < cnt && jj < DD)
                        A2[np][cl][jj] = (half_t)cell_update(acc2[i], c2r[i]);
                }
            }
            if (w == 7 && g2 == 2 && I >= 1) {       // cols 200,201 -> out(I-1)
                const int s = I - 1;
                obuf[(s >> 5) & 1][cl][(s & 31) * 2 + 0] = acc2[0][0];
                obuf[(s >> 5) & 1][cl][(s & 31) * 2 + 1] = acc2[0][1];
            }
        }
        // update1(I+1): per-lane -> h1(I+1) -> AH[np]
        if (I < TT) {
#pragma unroll
            for (int i = 0; i < 2; ++i) {
                const int jj = (tbase + i) * 4 + g2;
                if (i < cnt && jj < DD)
                    AH[np][cl][jj] = (half_t)cell_update(acc1[i], c1r[i]);
            }
            // x-stage: wave 7, g2==3 lanes (jj=51 -> no update item): x(I+2) -> AH[np]
            if (w == 7 && g2 == 3 && (I + 2) < TT) {
                const int r = lane - 48, tn = I + 2;
                const float* xs = &xbuf[(tn >> 5) & 1][r][(tn & 31) * 2];
                AH[np][r][50] = (half_t)xs[0];
                AH[np][r][51] = (half_t)xs[1];
            }
            if (hp) {
                const int idx = tid - 256, xr = idx >> 4, xq = idx & 15;
                *(f32x4*)&xbuf[(((I >> 5) + 1) & 1)][xr][xq * 4] = xpre;
            }
        }
        __syncthreads();   // the ONE barrier: h1(I+1), h2(I) published
    }

    // final flush: steps TT-32..TT-1 live in obuf[1]
    if (tid >= 256) {
        const int fr = (tid - 256) >> 4, fq = (tid - 256) & 15;
        const f32x4 v = *(const f32x4*)&obuf[1][fr][fq * 4];
        *(f32x4*)(out + (size_t)(bg0 + fr) * (TT * 2) + (TT - KF) * 2 + fq * 4) = v;
    }
}

extern "C" void kernel_launch(void* const* d_in, const int* in_sizes, int n_in,
                              void* d_out, int out_size, void* d_ws, size_t ws_size,
                              hipStream_t stream) {
    const float* x     = (const float*)d_in[0];
    const float* W_ih1 = (const float*)d_in[1];
    const float* W_hh1 = (const float*)d_in[2];
    const float* b_ih1 = (const float*)d_in[3];
    const float* b_hh1 = (const float*)d_in[4];
    const float* W_ih2 = (const float*)d_in[5];
    const float* W_hh2 = (const float*)d_in[6];
    const float* b_ih2 = (const float*)d_in[7];
    const float* b_hh2 = (const float*)d_in[8];
    const float* W_lin = (const float*)d_in[9];
    const float* b_lin = (const float*)d_in[10];
    float* out = (float*)d_out;

    const int B = in_sizes[0] / (TT * 2);   // 4096
    const int blocks = B / NB;              // 256

    hipLaunchKernelGGL(lstm_mfma_kernel, dim3(blocks), dim3(512), 0, stream,
                       x, W_ih1, W_hh1, b_ih1, b_hh1,
                       W_ih2, W_hh2, b_ih2, b_hh2, W_lin, b_lin, out);
}

// Round 8
// 796.751 us; speedup vs baseline: 12.9272x; 1.1171x over previous
//
#include <hip/hip_runtime.h>
#include <stdint.h>

#define DD 50
#define TT 1024
#define NB 16            // batch rows per block = MFMA M (full tile)
#define KF 32            // x-prefetch / out-flush chunk (steps)

typedef _Float16 half_t;
typedef __attribute__((ext_vector_type(8))) _Float16 f16x8;
typedef __attribute__((ext_vector_type(4))) float    f32x4;

#define AHS 72           // K=64: h1(50) | x(2) | 1@52 | pad — 144B rows (16B aligned)
#define A2S 72           // K=64: h2(50) | pad
#define OBW 68           // obuf row stride (f32)

__device__ __forceinline__ float rcp_f(float x)  { return __builtin_amdgcn_rcpf(x); }
__device__ __forceinline__ float exp2_f(float x) { return __builtin_amdgcn_exp2f(x); }

// Fused LSTM cell update, rcp-merged: 5 exp2 + 3 rcp per cell.
__device__ __forceinline__ float cell_update(const f32x4 acc, float& c) {
    const float a   = exp2_f(-1.4426950f * acc[0]);
    const float b   = exp2_f( 2.8853901f * acc[2]);
    const float t   = 1.0f + a;
    const float pig = (b - 1.0f) * rcp_f(t + t * b);
    const float pf  = rcp_f(1.0f + exp2_f(-1.4426950f * acc[1]));
    const float cn  = pf * c + pig;
    c = cn;
    const float o_  = exp2_f(-1.4426950f * acc[3]);
    const float e   = exp2_f( 2.8853901f * cn);
    const float t2  = 1.0f + o_;
    return (e - 1.0f) * rcp_f(t2 + t2 * e);
}

// 16 waves: waves 0-12 own ONE 16-col N-tile each (tile 12 = jj 48,49 + head
// cols 200,201); waves 13-15 are service-only. Gate columns interleaved
// col' = 4*jj + gate; MFMA with swapped operands (weights first):
// lane (cl,g2) of tile-wave w holds acc[r] = gate r of (b=cl, jj=4w+g2) —
// cell update fully per-lane. Shared-K trick: AH=[h1|x|1@52] feeds GEMM1 and
// GEMM2 kt0/1 (x rows zero in B2, biases at k=52); A2=[h2] feeds kt2/3.
// One barrier per pipelined interval; parity is compile-time via 2x unroll.

__global__ __launch_bounds__(1024, 1)
void lstm_mfma_kernel(const float* __restrict__ x,
                      const float* __restrict__ W_ih1, const float* __restrict__ W_hh1,
                      const float* __restrict__ b_ih1, const float* __restrict__ b_hh1,
                      const float* __restrict__ W_ih2, const float* __restrict__ W_hh2,
                      const float* __restrict__ b_ih2, const float* __restrict__ b_hh2,
                      const float* __restrict__ W_lin, const float* __restrict__ b_lin,
                      float* __restrict__ out)
{
    const int tid  = threadIdx.x;
    const int lane = tid & 63;
    const int w    = tid >> 6;           // 0..15
    const int bg0  = blockIdx.x * NB;
    const int cl   = lane & 15;          // batch row (n)
    const int g2   = lane >> 4;          // k-group / jj offset within tile

    __shared__ half_t AH[2][NB][AHS];
    __shared__ half_t A2[2][NB][A2S];
    __shared__ float  obuf[2][NB][OBW];
    __shared__ float  xbuf[2][NB][KF*2];

    const bool isComp = (w < 13);
    const int  tile   = isComp ? w : 0;
    const int  jj     = tile * 4 + g2;
    const bool doUpd  = isComp && (jj < DD);
    const bool headLn = (w == 12) && (g2 == 2);    // lanes holding cols 200,201
    const int  xr     = (tid - 768) >> 4;          // service row   (tid>=768)
    const int  xq     = tid & 15;                  // service 16B quarter

    // ---- B fragments (one tile per wave) ----
    f16x8 b1f[2], b2f[4];
    {
        const int  colp  = tile * 16 + cl;
        const bool valid = isComp && (colp < 200);
        const bool headB = isComp && (colp >= 200) && (colp <= 201);
        const int  g     = (colp & 3) * DD + (colp >> 2);
        // B1 over AH-k: W_hh1 | W_ih1@50,51 | bias1@52
#pragma unroll
        for (int kt = 0; kt < 2; ++kt)
#pragma unroll
            for (int j = 0; j < 8; ++j) {
                const int k = kt * 32 + g2 * 8 + j;
                float v = 0.f;
                if (valid) {
                    if (k < DD)          v = W_hh1[g * DD + k];
                    else if (k < DD + 2) v = W_ih1[g * 2 + (k - DD)];
                    else if (k == 52)    v = b_ih1[g] + b_hh1[g];
                }
                b1f[kt][j] = (half_t)v;
            }
        // B2 kt0/1 over AH-k: W_ih2 | zeros@50,51 | bias2@52 (head: b_lin@52)
#pragma unroll
        for (int kt = 0; kt < 2; ++kt)
#pragma unroll
            for (int j = 0; j < 8; ++j) {
                const int k = kt * 32 + g2 * 8 + j;
                float v = 0.f;
                if (k < DD) {
                    if (valid) v = W_ih2[g * DD + k];
                } else if (k == 52) {
                    if (valid)      v = b_ih2[g] + b_hh2[g];
                    else if (headB) v = b_lin[colp - 200];
                }
                b2f[kt][j] = (half_t)v;
            }
        // B2 kt2/3 over A2-k (h2): W_hh2 (head: W_lin)
#pragma unroll
        for (int kt = 2; kt < 4; ++kt)
#pragma unroll
            for (int j = 0; j < 8; ++j) {
                const int kk = (kt - 2) * 32 + g2 * 8 + j;
                float v = 0.f;
                if (kk < DD) {
                    if (valid)      v = W_hh2[g * DD + kk];
                    else if (headB) v = W_lin[(colp - 200) * DD + kk];
                }
                b2f[kt][j] = (half_t)v;
            }
    }

    // ---- init ----
    for (int idx = tid; idx < 2 * NB * AHS; idx += 1024) ((half_t*)AH)[idx] = (half_t)0.f;
    for (int idx = tid; idx < 2 * NB * A2S; idx += 1024) ((half_t*)A2)[idx] = (half_t)0.f;
    if (tid >= 768) {
        const f32x4 v = *(const f32x4*)(x + (size_t)(bg0 + xr) * (TT * 2) + xq * 4);
        *(f32x4*)&xbuf[0][xr][xq * 4] = v;
    }
    __syncthreads();
    if (tid < NB) {
        AH[0][tid][52] = (half_t)1.0f; AH[1][tid][52] = (half_t)1.0f;
        AH[1][tid][50] = (half_t)xbuf[0][tid][0];    // x(0) at parity of I=-1
        AH[1][tid][51] = (half_t)xbuf[0][tid][1];
    }
    __syncthreads();

    float c1 = 0.f, c2 = 0.f;

#define LSTM_STEP(PC)                                                              \
    {                                                                               \
        constexpr int P = (PC), NP = (PC) ^ 1;                                      \
        if (((I & 31) == 1) && I >= 33 && tid >= 768) {                             \
            const f32x4 v = *(const f32x4*)&obuf[((I - 33) >> 5) & 1][xr][xq * 4];  \
            *(f32x4*)(out + (size_t)(bg0 + xr) * (TT * 2) + (I - 33) * 2 + xq * 4) = v; \
        }                                                                           \
        f32x4 xpre; bool hp = false;                                                \
        if (((I & 31) == 0) && I >= 0 && tid >= 768) {                              \
            const int chunk = (I >> 5) + 1;                                         \
            if (chunk < TT / KF) {                                                  \
                hp = true;                                                          \
                xpre = *(const f32x4*)(x + (size_t)(bg0 + xr) * (TT * 2) + chunk * (KF * 2) + xq * 4); \
            }                                                                       \
        }                                                                           \
        f32x4 acc1, acc2;                                                           \
        if (isComp) {                                                               \
            const f16x8 a0 = *(const f16x8*)&AH[P][cl][g2 * 8];                     \
            const f16x8 a1 = *(const f16x8*)&AH[P][cl][32 + g2 * 8];                \
            const f16x8 h0 = *(const f16x8*)&A2[P][cl][g2 * 8];                     \
            const f16x8 h1 = *(const f16x8*)&A2[P][cl][32 + g2 * 8];                \
            if (I >= 0) {                                                           \
                f32x4 z = {0.f, 0.f, 0.f, 0.f};                                     \
                z = __builtin_amdgcn_mfma_f32_16x16x32_f16(b2f[2], h0, z, 0, 0, 0); \
                z = __builtin_amdgcn_mfma_f32_16x16x32_f16(b2f[3], h1, z, 0, 0, 0); \
                z = __builtin_amdgcn_mfma_f32_16x16x32_f16(b2f[0], a0, z, 0, 0, 0); \
                z = __builtin_amdgcn_mfma_f32_16x16x32_f16(b2f[1], a1, z, 0, 0, 0); \
                acc2 = z;                                                           \
            }                                                                       \
            if (I < TT) {                                                           \
                f32x4 z = {0.f, 0.f, 0.f, 0.f};                                     \
                z = __builtin_amdgcn_mfma_f32_16x16x32_f16(b1f[0], a0, z, 0, 0, 0); \
                z = __builtin_amdgcn_mfma_f32_16x16x32_f16(b1f[1], a1, z, 0, 0, 0); \
                acc1 = z;                                                           \
            }                                                                       \
        }                                                                           \
        if (I >= 0) {                                                               \
            if (I < TT && doUpd) A2[NP][cl][jj] = (half_t)cell_update(acc2, c2);    \
            if (headLn && I >= 1) {                                                 \
                const int s = I - 1;                                                \
                obuf[(s >> 5) & 1][cl][(s & 31) * 2 + 0] = acc2[0];                 \
                obuf[(s >> 5) & 1][cl][(s & 31) * 2 + 1] = acc2[1];                 \
            }                                                                       \
        }                                                                           \
        if (I < TT) {                                                               \
            if (doUpd) AH[NP][cl][jj] = (half_t)cell_update(acc1, c1);              \
            if (w == 13 && lane < 16 && (I + 2) < TT) {                             \
                const int tn = I + 2;                                               \
                const float* xs = &xbuf[(tn >> 5) & 1][lane][(tn & 31) * 2];        \
                AH[NP][lane][50] = (half_t)xs[0];                                   \
                AH[NP][lane][51] = (half_t)xs[1];                                   \
            }                                                                       \
            if (hp) *(f32x4*)&xbuf[((I >> 5) + 1) & 1][xr][xq * 4] = xpre;          \
        }                                                                           \
        __syncthreads();                                                            \
    }

    // intervals I = -1 .. TT (1026 total = 513 pairs); first of each pair is odd
    for (int I = -1; I <= TT; ) {
        LSTM_STEP(1); ++I;
        LSTM_STEP(0); ++I;
    }
#undef LSTM_STEP

    // final flush: steps TT-32..TT-1 live in obuf[1]
    if (tid >= 768) {
        const f32x4 v = *(const f32x4*)&obuf[1][xr][xq * 4];
        *(f32x4*)(out + (size_t)(bg0 + xr) * (TT * 2) + (TT - KF) * 2 + xq * 4) = v;
    }
}

extern "C" void kernel_launch(void* const* d_in, const int* in_sizes, int n_in,
                              void* d_out, int out_size, void* d_ws, size_t ws_size,
                              hipStream_t stream) {
    const float* x     = (const float*)d_in[0];
    const float* W_ih1 = (const float*)d_in[1];
    const float* W_hh1 = (const float*)d_in[2];
    const float* b_ih1 = (const float*)d_in[3];
    const float* b_hh1 = (const float*)d_in[4];
    const float* W_ih2 = (const float*)d_in[5];
    const float* W_hh2 = (const float*)d_in[6];
    const float* b_ih2 = (const float*)d_in[7];
    const float* b_hh2 = (const float*)d_in[8];
    const float* W_lin = (const float*)d_in[9];
    const float* b_lin = (const float*)d_in[10];
    float* out = (float*)d_out;

    const int B = in_sizes[0] / (TT * 2);   // 4096
    const int blocks = B / NB;              // 256

    hipLaunchKernelGGL(lstm_mfma_kernel, dim3(blocks), dim3(1024), 0, stream,
                       x, W_ih1, W_hh1, b_ih1, b_hh1,
                       W_ih2, W_hh2, b_ih2, b_hh2, W_lin, b_lin, out);
}